// Round 3
// baseline (83.137 us; speedup 1.0000x reference)
//
#include <hip/hip_runtime.h>
#include <math.h>

#define EMBED 1280
#define NHEAD 20
#define HDIM 64
#define LENC 8192
#define CHUNK 128
#define NCHUNK (LENC / CHUNK)   // 64
#define PREC 72                 // floats per partial record: [M,S,pad,pad,o[64]]
#define QSCALE 0.125f           // 64^-0.5

// ---------------------------------------------------------------------------
// matvec: one row per block, 256 threads, float4 loads.
// y[row] = scale * (W[row,:] . x + b[row])
// Optionally zeroes the flash-decode counters (stream-ordered before attn).
// ---------------------------------------------------------------------------
__global__ __launch_bounds__(256) void matvec_row(
    const float* __restrict__ W, const float* __restrict__ x,
    const float* __restrict__ b, float* __restrict__ y, float scale,
    int* __restrict__ cnt_zero) {
  if (cnt_zero != nullptr && blockIdx.x < NHEAD && threadIdx.x == 0)
    __hip_atomic_store(&cnt_zero[blockIdx.x], 0, __ATOMIC_RELEASE,
                       __HIP_MEMORY_SCOPE_AGENT);
  int row = blockIdx.x;
  int t = threadIdx.x;
  int w = t >> 6, lane = t & 63;
  const float4* Wr = reinterpret_cast<const float4*>(W + (size_t)row * EMBED);
  const float4* x4 = reinterpret_cast<const float4*>(x);
  // 320 float4 per row: threads 0..255 cover [0,256), threads 0..63 cover [256,320)
  float4 wv = Wr[t], xv = x4[t];
  float acc = wv.x * xv.x + wv.y * xv.y + wv.z * xv.z + wv.w * xv.w;
  if (t < 64) {
    float4 wv2 = Wr[256 + t], xv2 = x4[256 + t];
    acc += wv2.x * xv2.x + wv2.y * xv2.y + wv2.z * xv2.z + wv2.w * xv2.w;
  }
#pragma unroll
  for (int msk = 32; msk > 0; msk >>= 1) acc += __shfl_xor(acc, msk);
  __shared__ float red[4];
  if (lane == 0) red[w] = acc;
  __syncthreads();
  if (t == 0) y[row] = scale * (red[0] + red[1] + red[2] + red[3] + b[row]);
}

// ---------------------------------------------------------------------------
// Flash-decode partial + fused last-block combine.
// One block per (head, chunk of 128 keys). float4 loads: 16 lanes per row.
// Record: [M, S, pad, pad, o[64]]. Last block per head combines -> attn_out.
// ---------------------------------------------------------------------------
__global__ __launch_bounds__(256) void attn_partial(
    const float* __restrict__ K, const float* __restrict__ V,
    const float* __restrict__ q, float* __restrict__ part,
    int* __restrict__ cnt, float* __restrict__ attn_out) {
  int blk = blockIdx.x;  // 0..NHEAD*NCHUNK-1
  int h = blk / NCHUNK;
  int c = blk % NCHUNK;
  int tid = threadIdx.x;
  int w = tid >> 6;       // wave 0..3
  int lane = tid & 63;
  int grp = lane >> 4;    // row-group 0..3 within wave
  int l16 = lane & 15;    // float4 index within row

  __shared__ float sc[CHUNK];
  __shared__ float red[8];
  __shared__ float4 ovec[4][16];
  __shared__ int sWon;

  const float4* Kh4 = reinterpret_cast<const float4*>(
      K + (size_t)h * LENC * HDIM + (size_t)c * CHUNK * HDIM);
  const float4* Vh4 = reinterpret_cast<const float4*>(
      V + (size_t)h * LENC * HDIM + (size_t)c * CHUNK * HDIM);
  float4 qv = reinterpret_cast<const float4*>(q + h * HDIM)[l16];

  // --- scores: wave w covers rows [w*32, w*32+32), 4 rows per iter ---
#pragma unroll
  for (int it = 0; it < CHUNK / 16; ++it) {   // 8 iters
    int row = w * (CHUNK / 4) + it * 4 + grp;
    float4 kv = Kh4[row * 16 + l16];
    float s = kv.x * qv.x + kv.y * qv.y + kv.z * qv.z + kv.w * qv.w;
    s += __shfl_xor(s, 1);
    s += __shfl_xor(s, 2);
    s += __shfl_xor(s, 4);
    s += __shfl_xor(s, 8);
    if (l16 == 0) sc[row] = s;
  }
  __syncthreads();

  // --- block max over 128 scores ---
  float m = (tid < CHUNK) ? sc[tid] : -INFINITY;
#pragma unroll
  for (int msk = 32; msk > 0; msk >>= 1) m = fmaxf(m, __shfl_xor(m, msk));
  if (lane == 0) red[w] = m;
  __syncthreads();
  float M = fmaxf(fmaxf(red[0], red[1]), fmaxf(red[2], red[3]));

  // --- exp + block sum ---
  float e = (tid < CHUNK) ? expf(sc[tid] - M) : 0.f;
  if (tid < CHUNK) sc[tid] = e;
  float ssum = e;
#pragma unroll
  for (int msk = 32; msk > 0; msk >>= 1) ssum += __shfl_xor(ssum, msk);
  if (lane == 0) red[4 + w] = ssum;
  __syncthreads();
  float S = red[4] + red[5] + red[6] + red[7];

  // --- P @ V partial: lane accumulates out dims [l16*4, l16*4+4) ---
  float4 acc = make_float4(0.f, 0.f, 0.f, 0.f);
#pragma unroll
  for (int it = 0; it < CHUNK / 16; ++it) {
    int row = w * (CHUNK / 4) + it * 4 + grp;
    float4 vv = Vh4[row * 16 + l16];
    float p = sc[row];
    acc.x += p * vv.x; acc.y += p * vv.y; acc.z += p * vv.z; acc.w += p * vv.w;
  }
#pragma unroll
  for (int msk = 16; msk <= 32; msk <<= 1) {
    acc.x += __shfl_xor(acc.x, msk);
    acc.y += __shfl_xor(acc.y, msk);
    acc.z += __shfl_xor(acc.z, msk);
    acc.w += __shfl_xor(acc.w, msk);
  }
  if (grp == 0) ovec[w][l16] = acc;
  __syncthreads();

  if (w == 0 && grp == 0) {
    float4 o0 = ovec[0][l16], o1 = ovec[1][l16], o2 = ovec[2][l16], o3 = ovec[3][l16];
    float4 o = make_float4(o0.x + o1.x + o2.x + o3.x, o0.y + o1.y + o2.y + o3.y,
                           o0.z + o1.z + o2.z + o3.z, o0.w + o1.w + o2.w + o3.w);
    float* p = part + (size_t)(h * NCHUNK + c) * PREC;
    if (tid == 0) { p[0] = M; p[1] = S; }
    reinterpret_cast<float4*>(p + 4)[l16] = o;
  }
  __syncthreads();

  // --- last block for this head combines the 64 partials ---
  if (tid == 0) {
    __threadfence();  // make this block's record visible at agent scope
    int old = atomicAdd(&cnt[h], 1);
    sWon = (old == NCHUNK - 1) ? 1 : 0;
  }
  __syncthreads();
  if (sWon) {
    __threadfence();  // acquire: see all other blocks' records
    if (tid < HDIM) {
      const float* p = part + (size_t)h * NCHUNK * PREC;
      float Mg = -INFINITY;
#pragma unroll
      for (int cc = 0; cc < NCHUNK; ++cc) Mg = fmaxf(Mg, p[cc * PREC]);
      float Sg = 0.f, o = 0.f;
#pragma unroll
      for (int cc = 0; cc < NCHUNK; ++cc) {
        float f = expf(p[cc * PREC] - Mg);
        Sg += p[cc * PREC + 1] * f;
        o += p[cc * PREC + 4 + tid] * f;
      }
      attn_out[h * HDIM + tid] = o / Sg;
    }
  }
}

// ---------------------------------------------------------------------------

extern "C" void kernel_launch(void* const* d_in, const int* in_sizes, int n_in,
                              void* d_out, int out_size, void* d_ws, size_t ws_size,
                              hipStream_t stream) {
  const float* hs    = (const float*)d_in[0];  // [1280]
  const float* Kc    = (const float*)d_in[1];  // [20,8192,64]
  const float* Vc    = (const float*)d_in[2];  // [20,8192,64]
  const float* q_w   = (const float*)d_in[3];  // [1280,1280]
  const float* q_b   = (const float*)d_in[4];  // [1280]
  const float* out_w = (const float*)d_in[5];  // [1280,1280]
  const float* out_b = (const float*)d_in[6];  // [1280]
  float* out = (float*)d_out;                  // [1280]

  float* ws = (float*)d_ws;
  int*   cnt      = (int*)ws;          // [20] flash-decode arrival counters
  float* qv       = ws + 32;           // 1280
  float* attn_out = ws + 32 + EMBED;   // 1280
  float* part     = ws + 32 + 2 * EMBED;  // 20*64*72 floats (16B-aligned)

  // 1. q projection (+ scale); also zeroes cnt[] before attn_partial runs
  matvec_row<<<EMBED, 256, 0, stream>>>(q_w, hs, q_b, qv, QSCALE, cnt);
  // 2. flash-decode partials + fused per-head combine
  attn_partial<<<NHEAD * NCHUNK, 256, 0, stream>>>(Kc, Vc, qv, part, cnt, attn_out);
  // 3. output projection
  matvec_row<<<EMBED, 256, 0, stream>>>(out_w, attn_out, out_b, out, 1.0f, nullptr);
}

// Round 4
// 29.296 us; speedup vs baseline: 2.8378x; 2.8378x over previous
//
#include <hip/hip_runtime.h>
#include <math.h>

#define EMBED 1280
#define NHEAD 20
#define HDIM 64
#define LENC 8192
#define CHUNK 128               // rows per block (4 independent waves x 32 rows)
#define NBLK (LENC / CHUNK)     // 64 blocks per head
#define NREC 256                // partial records per head (one per wave)
#define PREC 72                 // floats per record: [M,S,pad,pad,o[64]]
#define QSCALE 0.125f           // 64^-0.5

// ---------------------------------------------------------------------------
// matvec: one row per block, 256 threads, float4 loads.
// y[row] = scale * (W[row,:] . x + b[row])
// ---------------------------------------------------------------------------
__global__ __launch_bounds__(256) void matvec_row(
    const float* __restrict__ W, const float* __restrict__ x,
    const float* __restrict__ b, float* __restrict__ y, float scale) {
  int row = blockIdx.x;
  int t = threadIdx.x;
  int w = t >> 6, lane = t & 63;
  const float4* Wr = reinterpret_cast<const float4*>(W + (size_t)row * EMBED);
  const float4* x4 = reinterpret_cast<const float4*>(x);
  float4 wv = Wr[t], xv = x4[t];
  float acc = wv.x * xv.x + wv.y * xv.y + wv.z * xv.z + wv.w * xv.w;
  if (t < 64) {
    float4 wv2 = Wr[256 + t], xv2 = x4[256 + t];
    acc += wv2.x * xv2.x + wv2.y * xv2.y + wv2.z * xv2.z + wv2.w * xv2.w;
  }
#pragma unroll
  for (int msk = 32; msk > 0; msk >>= 1) acc += __shfl_xor(acc, msk);
  __shared__ float red[4];
  if (lane == 0) red[w] = acc;
  __syncthreads();
  if (t == 0) y[row] = scale * (red[0] + red[1] + red[2] + red[3] + b[row]);
}

// ---------------------------------------------------------------------------
// Flash-decode partial: each WAVE independently owns 32 keys.
// No LDS, no __syncthreads, no fences. 16 float4 loads in flight per lane.
// 16 lanes span one 64-float row; lane group grp handles rows it*4+grp.
// Record per wave: [M, S, pad, pad, o[64]] (o unnormalized).
// ---------------------------------------------------------------------------
__global__ __launch_bounds__(256) void attn_partial(
    const float* __restrict__ K, const float* __restrict__ V,
    const float* __restrict__ q, float* __restrict__ part) {
  int blk = blockIdx.x;   // 0..NHEAD*NBLK-1
  int h = blk / NBLK;
  int c = blk % NBLK;
  int tid = threadIdx.x;
  int w = tid >> 6;       // wave 0..3
  int lane = tid & 63;
  int grp = lane >> 4;    // row-group 0..3 within wave
  int l16 = lane & 15;    // float4 index within row

  size_t row0 = (size_t)c * CHUNK + (size_t)w * 32;  // first of this wave's 32 rows
  const float4* Kh4 = reinterpret_cast<const float4*>(K + (size_t)h * LENC * HDIM) + row0 * 16;
  const float4* Vh4 = reinterpret_cast<const float4*>(V + (size_t)h * LENC * HDIM) + row0 * 16;
  float4 qv = reinterpret_cast<const float4*>(q + h * HDIM)[l16];

  // issue all K loads, then all V loads (V consumed only after softmax)
  float4 kreg[8], vreg[8];
#pragma unroll
  for (int it = 0; it < 8; ++it) kreg[it] = Kh4[(it * 4 + grp) * 16 + l16];
#pragma unroll
  for (int it = 0; it < 8; ++it) vreg[it] = Vh4[(it * 4 + grp) * 16 + l16];

  // scores for my group's 8 rows (replicated across the 16 lanes of the group)
  float s[8];
#pragma unroll
  for (int it = 0; it < 8; ++it) {
    float t = kreg[it].x * qv.x + kreg[it].y * qv.y + kreg[it].z * qv.z + kreg[it].w * qv.w;
    t += __shfl_xor(t, 1);
    t += __shfl_xor(t, 2);
    t += __shfl_xor(t, 4);
    t += __shfl_xor(t, 8);
    s[it] = t;
  }

  // wave-local softmax over 32 rows (reduce across the 4 groups: xor 16, 32)
  float m = s[0];
#pragma unroll
  for (int it = 1; it < 8; ++it) m = fmaxf(m, s[it]);
  m = fmaxf(m, __shfl_xor(m, 16));
  m = fmaxf(m, __shfl_xor(m, 32));

  float e[8], ssum = 0.f;
#pragma unroll
  for (int it = 0; it < 8; ++it) { e[it] = expf(s[it] - m); ssum += e[it]; }
  ssum += __shfl_xor(ssum, 16);
  ssum += __shfl_xor(ssum, 32);

  // P @ V for my group's rows, dims [l16*4, l16*4+4)
  float4 o = make_float4(0.f, 0.f, 0.f, 0.f);
#pragma unroll
  for (int it = 0; it < 8; ++it) {
    o.x += e[it] * vreg[it].x;
    o.y += e[it] * vreg[it].y;
    o.z += e[it] * vreg[it].z;
    o.w += e[it] * vreg[it].w;
  }
#pragma unroll
  for (int msk = 16; msk <= 32; msk <<= 1) {
    o.x += __shfl_xor(o.x, msk);
    o.y += __shfl_xor(o.y, msk);
    o.z += __shfl_xor(o.z, msk);
    o.w += __shfl_xor(o.w, msk);
  }

  float* p = part + (size_t)(h * NREC + c * 4 + w) * PREC;
  if (grp == 0) {
    if (l16 == 0) { p[0] = m; p[1] = ssum; }
    reinterpret_cast<float4*>(p + 4)[l16] = o;
  }
}

// ---------------------------------------------------------------------------
// Combine 256 partials per head: 20 blocks x 256 threads.
// Thread t owns record t's (M,S); wave w accumulates o over records [64w,64w+64).
// ---------------------------------------------------------------------------
__global__ __launch_bounds__(256) void attn_combine(
    const float* __restrict__ part, float* __restrict__ attn_out) {
  int h = blockIdx.x;
  int tid = threadIdx.x;
  int w = tid >> 6, lane = tid & 63;
  const float* p = part + (size_t)h * NREC * PREC;

  __shared__ float fsh[NREC];
  __shared__ float redM[4], redS[4];
  __shared__ float osum[4][HDIM];

  float mt = p[tid * PREC];
  float st = p[tid * PREC + 1];
  float m = mt;
#pragma unroll
  for (int msk = 32; msk > 0; msk >>= 1) m = fmaxf(m, __shfl_xor(m, msk));
  if (lane == 0) redM[w] = m;
  __syncthreads();
  float Mg = fmaxf(fmaxf(redM[0], redM[1]), fmaxf(redM[2], redM[3]));

  float f = expf(mt - Mg);
  fsh[tid] = f;
  float sc = st * f;
#pragma unroll
  for (int msk = 32; msk > 0; msk >>= 1) sc += __shfl_xor(sc, msk);
  if (lane == 0) redS[w] = sc;
  __syncthreads();
  float Sg = redS[0] + redS[1] + redS[2] + redS[3];

  // o[lane] accumulated over this wave's 64 records (coalesced 256B reads)
  float o = 0.f;
#pragma unroll
  for (int r = 0; r < 64; ++r) {
    int rec = w * 64 + r;
    o += fsh[rec] * p[rec * PREC + 4 + lane];
  }
  osum[w][lane] = o;
  __syncthreads();
  if (w == 0) {
    float oo = osum[0][lane] + osum[1][lane] + osum[2][lane] + osum[3][lane];
    attn_out[h * HDIM + lane] = oo / Sg;
  }
}

// ---------------------------------------------------------------------------

extern "C" void kernel_launch(void* const* d_in, const int* in_sizes, int n_in,
                              void* d_out, int out_size, void* d_ws, size_t ws_size,
                              hipStream_t stream) {
  const float* hs    = (const float*)d_in[0];  // [1280]
  const float* Kc    = (const float*)d_in[1];  // [20,8192,64]
  const float* Vc    = (const float*)d_in[2];  // [20,8192,64]
  const float* q_w   = (const float*)d_in[3];  // [1280,1280]
  const float* q_b   = (const float*)d_in[4];  // [1280]
  const float* out_w = (const float*)d_in[5];  // [1280,1280]
  const float* out_b = (const float*)d_in[6];  // [1280]
  float* out = (float*)d_out;                  // [1280]

  float* ws = (float*)d_ws;
  float* qv       = ws;                 // 1280
  float* attn_out = ws + EMBED;         // 1280
  float* part     = ws + 2 * EMBED;     // 20*256*72 floats (16B-aligned)

  // 1. q projection (+ scale)
  matvec_row<<<EMBED, 256, 0, stream>>>(q_w, hs, q_b, qv, QSCALE);
  // 2. flash-decode partials (wave-independent, no barriers)
  attn_partial<<<NHEAD * NBLK, 256, 0, stream>>>(Kc, Vc, qv, part);
  // 3. combine 256 records per head
  attn_combine<<<NHEAD, 256, 0, stream>>>(part, attn_out);
  // 4. output projection
  matvec_row<<<EMBED, 256, 0, stream>>>(out_w, attn_out, out_b, out, 1.0f);
}